// Round 5
// baseline (108.358 us; speedup 1.0000x reference)
//
#include <hip/hip_runtime.h>

// Problem constants (reference: S, B, D, MAX_LEN, P = 4096, 64, 256, 4096, 8)
#define S_LEN 4096
#define BATCH 64
#define DIM 256
#define NPEAK 8
#define TOTAL4 (S_LEN * BATCH * DIM / 4)     // 16,777,216 float4 elements
#define NBLOCKS 2048
#define NTHREADS (NBLOCKS * 256)             // 2^19
#define ITERS (TOTAL4 / NTHREADS)            // 32 exactly

static_assert(TOTAL4 % NTHREADS == 0, "exact grid-stride trip count required");

typedef float f32x4 __attribute__((ext_vector_type(4)));

// Fused: out[s,b,d] = x[s,b,d] + pe[s,d] + count(s,b) * table[s,d]
// count(s,b) = #{ j : peaks[b,j] == s }; invalid peaks (outside [0,S)) never
// match any s in [0,S), so they contribute zero — matches reference incl dups.
//
// Layout invariants (grid*block = stride = 2^19):
//   lane = d4 -> (s,b) uniform per wave, cnt branch non-divergent
//   b, d4 invariant across iterations; s = s0 + it*128
//
// Round-2 lesson: explicit unroll-4 REGRESSED — keep the loop rolled.
// Round-3 lesson: store policy (nt vs cached) is neutral.
// Round-4 change: XCD-aware bijective block swizzle. pe row s is consumed by
// the 16-block group lbid/16 == s0; default round-robin spreads that group
// over all 8 XCD L2s -> pe fetched 8x (~32 MB HBM). Swizzle
// lbid = (h%8)*256 + h/8 puts each group on ONE XCD -> pe fetched once
// (~4 MB), saving ~28 MB (~5% of total traffic).
__global__ __launch_bounds__(256) void fused_pe_peak_kernel(
    const f32x4* __restrict__ x,
    const int*   __restrict__ peaks,
    const f32x4* __restrict__ pe,
    const f32x4* __restrict__ table,
    f32x4* __restrict__ out)
{
    // Bijective XCD swizzle over 2048 blocks (2048 % 8 == 0).
    const int h = blockIdx.x;
    const int lbid = (h & 7) * (NBLOCKS / 8) + (h >> 3);
    const int tid = lbid * 256 + threadIdx.x;

    const int b   = (tid >> 6) & (BATCH - 1);
    const int d4  = tid & (DIM / 4 - 1);
    const int s0  = tid >> 12;               // s(it) = s0 + it*128

    int pk[NPEAK];
    #pragma unroll
    for (int j = 0; j < NPEAK; ++j) pk[j] = peaks[b * NPEAK + j];

    #pragma unroll 1
    for (int it = 0; it < ITERS; ++it) {
        const int i = tid + it * NTHREADS;
        const int s = s0 + it * 128;
        f32x4 xv = __builtin_nontemporal_load(&x[i]);   // streamed, no reuse
        f32x4 pv = pe[(s << 6) + d4];                   // L2-resident, XCD-local
        f32x4 o = xv + pv;

        int cnt = 0;
        #pragma unroll
        for (int j = 0; j < NPEAK; ++j) cnt += (pk[j] == s) ? 1 : 0;
        if (cnt)                                         // wave-uniform, rare
            o += (float)cnt * table[(s << 6) + d4];

        __builtin_nontemporal_store(o, &out[i]);         // streamed, written once
    }
}

extern "C" void kernel_launch(void* const* d_in, const int* in_sizes, int n_in,
                              void* d_out, int out_size, void* d_ws, size_t ws_size,
                              hipStream_t stream) {
    const float* x     = (const float*)d_in[0];   // [S, B, D] f32
    const int* peaks   = (const int*)d_in[1];     // [B, P] i32
    const float* pe    = (const float*)d_in[2];   // [MAX_LEN, 1, D] f32
    const float* table = (const float*)d_in[3];   // [MAX_LEN, D] f32

    // grid*block = 2^19 exactly: required for the b/d4/s0 hoisting invariants.
    fused_pe_peak_kernel<<<NBLOCKS, 256, 0, stream>>>(
        (const f32x4*)x, peaks, (const f32x4*)pe, (const f32x4*)table,
        (f32x4*)d_out);
}

// Round 6
// 100.649 us; speedup vs baseline: 1.0766x; 1.0766x over previous
//
#include <hip/hip_runtime.h>

// Problem constants (reference: S, B, D, MAX_LEN, P = 4096, 64, 256, 4096, 8)
#define S_LEN 4096
#define BATCH 64
#define DIM 256
#define NPEAK 8
#define ROW4 (BATCH * DIM / 4)      // 4096 float4 per s-row
#define KITERS (ROW4 / 256)         // 16 iterations per block

typedef float f32x4 __attribute__((ext_vector_type(4)));

// One block per s-row. out[s,b,d] = x[s,b,d] + pe[s,d] + cnt(s,b)*table[s,d].
//
// Why this structure: pe[s][d4] and table[s][d4] depend only on (s, d4);
// with s fixed per block and d4 = tid&63 fixed per thread, both are loaded
// ONCE into registers. The streaming loop body is then exactly copy-shaped
// (nt-load x -> one packed add -> nt-store), no dependent per-iteration L2
// load. Peak counts for the row are built once in an LDS prologue from the
// 2 KB peaks array (L2-hot broadcast across blocks).
//
// Iteration k covers i_local = k*256 + tid within the row:
//   b  = i_local>>6 = 4k + (tid>>6)   (wave-uniform each iteration)
//   d4 = i_local&63 = tid&63          (constant)
//
// Lessons kept: rolled loop (r2: unroll regressed), nt streams (r3: neutral),
// no XCD swizzle (r4: regressed).
__global__ __launch_bounds__(256) void fused_pe_peak_kernel(
    const f32x4* __restrict__ x,
    const int*   __restrict__ peaks,
    const f32x4* __restrict__ pe,
    const f32x4* __restrict__ table,
    f32x4* __restrict__ out)
{
    const int s = blockIdx.x;                 // 0 .. S_LEN-1
    const int t = threadIdx.x;
    const int d4 = t & 63;
    const int w  = t >> 6;                    // wave id 0..3

    __shared__ int cnt[BATCH];
    __shared__ int anypeak;
    if (t < BATCH) cnt[t] = 0;
    if (t == 0) anypeak = 0;
    __syncthreads();
    #pragma unroll
    for (int j = t; j < BATCH * NPEAK; j += 256) {   // 2 probes/thread
        if (peaks[j] == s) {                          // invalid peaks never match
            atomicAdd(&cnt[j >> 3], 1);               // duplicates accumulate
            anypeak = 1;                              // benign race (all write 1)
        }
    }
    __syncthreads();

    const f32x4 pv = pe[(s << 6) + d4];       // once per block
    const size_t base = (size_t)s * ROW4;

    if (!anypeak) {
        // Common path (~87% of rows): pure copy + registered add.
        #pragma unroll 1
        for (int k = 0; k < KITERS; ++k) {
            const size_t i = base + k * 256 + t;
            f32x4 o = __builtin_nontemporal_load(&x[i]) + pv;
            __builtin_nontemporal_store(o, &out[i]);
        }
    } else {
        const f32x4 tv = table[(s << 6) + d4];
        #pragma unroll 1
        for (int k = 0; k < KITERS; ++k) {
            const size_t i = base + k * 256 + t;
            f32x4 o = __builtin_nontemporal_load(&x[i]) + pv;
            const int c = cnt[4 * k + w];     // wave-uniform LDS broadcast
            if (c) o += (float)c * tv;
            __builtin_nontemporal_store(o, &out[i]);
        }
    }
}

extern "C" void kernel_launch(void* const* d_in, const int* in_sizes, int n_in,
                              void* d_out, int out_size, void* d_ws, size_t ws_size,
                              hipStream_t stream) {
    const float* x     = (const float*)d_in[0];   // [S, B, D] f32
    const int* peaks   = (const int*)d_in[1];     // [B, P] i32
    const float* pe    = (const float*)d_in[2];   // [MAX_LEN, 1, D] f32
    const float* table = (const float*)d_in[3];   // [MAX_LEN, D] f32

    fused_pe_peak_kernel<<<S_LEN, 256, 0, stream>>>(
        (const f32x4*)x, peaks, (const f32x4*)pe, (const f32x4*)table,
        (f32x4*)d_out);
}